// Round 6
// baseline (307.352 us; speedup 1.0000x reference)
//
#include <hip/hip_runtime.h>

// R6: BARRIER-FREE attention — K/V MFMA fragments loaded directly from global
// (L1-shared across the block's 4 waves), P round-trip in wave-private LDS,
// cvt_pk_bf16 packing. GEMMs: BK=64 (8 iters, half the barrier drains) with
// XOR chunk swizzle compatible with global_load_lds contiguity.
#define DIM 512
#define NQ 2048
#define MA 2048
#define MS 256
#define QSCALE 0.06375864651f  // 512^-0.5 * log2(e)

typedef __attribute__((ext_vector_type(8))) short bf16x8;
typedef __attribute__((ext_vector_type(4))) float f32x4;
typedef __attribute__((ext_vector_type(16))) float f32x16;

__device__ __forceinline__ ushort f2b(float f) {
    uint u = __float_as_uint(f);
    u = (u + 0x7fffu + ((u >> 16) & 1u)) >> 16;
    return (ushort)u;
}

__device__ __forceinline__ uint pk2bf(float a, float b) {
#if __has_builtin(__builtin_amdgcn_cvt_pk_bf16_f32)
    typedef __attribute__((ext_vector_type(2))) __bf16 bf2;
    bf2 r = __builtin_amdgcn_cvt_pk_bf16_f32(a, b);
    uint u;
    __builtin_memcpy(&u, &r, 4);
    return u;
#else
    return ((__float_as_uint(a) + 0x8000u) >> 16) |
           ((__float_as_uint(b) + 0x8000u) & 0xffff0000u);
#endif
}

__device__ __forceinline__ void gload16(const ushort* g, ushort* l) {
    __builtin_amdgcn_global_load_lds(
        (const __attribute__((address_space(1))) void*)g,
        (__attribute__((address_space(3))) void*)l, 16, 0, 0);
}

// ---- fused cast: 6 weights + x + ac + scx -> contiguous bf16 region ----
__global__ __launch_bounds__(256) void cast_all(const float* __restrict__ w0,
                                                const float* __restrict__ w1,
                                                const float* __restrict__ w2,
                                                const float* __restrict__ w3,
                                                const float* __restrict__ w4,
                                                const float* __restrict__ w5,
                                                const float* __restrict__ x,
                                                const float* __restrict__ ac,
                                                const float* __restrict__ scx,
                                                ushort* __restrict__ dst) {
    int i = blockIdx.x * 256 + threadIdx.x;  // float4 index, 2621440 total
    const float* s;
    int o;
    if (i < 393216) {
        int w = i >> 16;
        s = w < 3 ? (w == 0 ? w0 : (w == 1 ? w1 : w2))
                  : (w == 3 ? w3 : (w == 4 ? w4 : w5));
        o = i & 65535;
    } else if (i < 1441792) { s = x;   o = i - 393216; }
    else if (i < 2490368)   { s = ac;  o = i - 1441792; }
    else                    { s = scx; o = i - 2490368; }
    float4 v = ((const float4*)s)[o];
    ushort4 u;
    u.x = f2b(v.x); u.y = f2b(v.y); u.z = f2b(v.z); u.w = f2b(v.w);
    ((ushort4*)dst)[i] = u;
}

// ---- fused GEMM: C = A @ B^T + bias, 128x128 tile, K=512, BK=64 ----
struct GD {
    const ushort* A; const ushort* B; const float* bias; void* out;
    long sB, sO;
    int N, bx, by, blk0, biasrow, scaleq, outf32, pad;
};

__global__ __launch_bounds__(256) void gemm_fused(GD d0, GD d1, GD d2, GD d3, GD d4) {
    __shared__ ushort At[128 * 64];
    __shared__ ushort Bt[128 * 64];
    GD d = d0;
    int bid = blockIdx.x;
    if (bid >= d1.blk0) d = d1;
    if (bid >= d2.blk0) d = d2;
    if (bid >= d3.blk0) d = d3;
    if (bid >= d4.blk0) d = d4;
    int local = bid - d.blk0;
    int x = local % d.bx;
    int rem = local / d.bx;
    int y = rem % d.by;
    int z = rem / d.by;

    int t = threadIdx.x;
    int wv = t >> 6, ln = t & 63, l = ln & 15, g = ln >> 4;
    int wrow = wv & 1, wcol = wv >> 1;
    int row0 = x * 128, col0 = y * 128;
    // staging: call j covers rows j*32 + (t>>3), phys chunk t&7 holds global
    // chunk (t&7)^(row&7); LDS dest = j*4096B + t*16B (wave-contiguous)
    int srw = t >> 3;
    int chs = ((t & 7) ^ ((t >> 3) & 7)) * 8;  // swizzled source chunk offset
    const ushort* Ab = d.A;
    const ushort* Bb = d.B + (size_t)z * d.sB;
    int N = d.N;

    f32x4 acc[4][4];
#pragma unroll
    for (int i = 0; i < 4; i++)
#pragma unroll
        for (int j = 0; j < 4; j++) acc[i][j] = (f32x4){0, 0, 0, 0};

    for (int k0 = 0; k0 < 512; k0 += 64) {
        __syncthreads();
#pragma unroll
        for (int j = 0; j < 4; j++) {
            int r = j * 32 + srw;
            gload16(Ab + (size_t)(row0 + r) * 512 + k0 + chs, At + j * 2048 + t * 8);
            gload16(Bb + (size_t)(col0 + r) * 512 + k0 + chs, Bt + j * 2048 + t * 8);
        }
        __syncthreads();
#pragma unroll
        for (int kb = 0; kb < 2; kb++) {
            int rc = ((4 * kb + g) ^ (l & 7)) * 8;  // reader un-swizzle
            bf16x8 ar[4], br[4];
#pragma unroll
            for (int i = 0; i < 4; i++)
                ar[i] = *(const bf16x8*)(At + (wrow * 64 + i * 16 + l) * 64 + rc);
#pragma unroll
            for (int j = 0; j < 4; j++)
                br[j] = *(const bf16x8*)(Bt + (wcol * 64 + j * 16 + l) * 64 + rc);
#pragma unroll
            for (int i = 0; i < 4; i++)
#pragma unroll
                for (int j = 0; j < 4; j++)
                    acc[i][j] = __builtin_amdgcn_mfma_f32_16x16x32_bf16(ar[i], br[j], acc[i][j], 0, 0, 0);
        }
    }
#pragma unroll
    for (int i = 0; i < 4; i++) {
#pragma unroll
        for (int j = 0; j < 4; j++) {
            int row = row0 + wrow * 64 + i * 16 + g * 4;
            int col = col0 + wcol * 64 + j * 16 + l;
#pragma unroll
            for (int r = 0; r < 4; r++) {
                float bv = d.biasrow ? d.bias[row + r] : d.bias[col];
                float o = acc[i][j][r] + bv;
                if (d.scaleq) o *= QSCALE;
                if (d.outf32)
                    ((float*)d.out + (size_t)z * d.sO)[(size_t)(row + r) * N + col] = o;
                else
                    ((ushort*)d.out + (size_t)z * d.sO)[(size_t)(row + r) * N + col] = f2b(o);
            }
        }
    }
}

// ---- attention: barrier-free, K/V frags direct from global (L1-shared),
// P in wave-private LDS, 32x32x16 MFMA, wave owns 32 q rows ----
__device__ __forceinline__ void attn_ctx32(const ushort* __restrict__ kp,
                                           const ushort* __restrict__ vp,
                                           int M,
                                           const bf16x8 (&aq)[4],
                                           ushort* __restrict__ Pw,
                                           f32x16 (&o)[2], float& li,
                                           int l5, int hi) {
    for (int mt = 0; mt < M; mt += 64) {
        // V fragments for this tile (issued early; consumed in PV)
        bf16x8 vf[2][4];
#pragma unroll
        for (int dn = 0; dn < 2; dn++)
#pragma unroll
            for (int kc = 0; kc < 4; kc++)
                vf[dn][kc] = *(const bf16x8*)(vp + (size_t)(32 * dn) * M + mt + kc * 16);
#pragma unroll
        for (int c = 0; c < 2; c++) {
            bf16x8 kf[4];
#pragma unroll
            for (int kd = 0; kd < 4; kd++)
                kf[kd] = *(const bf16x8*)(kp + (size_t)(mt + 32 * c) * DIM + kd * 16);
            f32x16 s;
#pragma unroll
            for (int i = 0; i < 16; i++) s[i] = 0.f;
#pragma unroll
            for (int kd = 0; kd < 4; kd++)
                s = __builtin_amdgcn_mfma_f32_32x32x16_bf16(kf[kd], aq[kd], s, 0, 0, 0);
            // lane holds q=l5 (col); quad m -> ctx_local = 8m + 4hi + 0..3
#pragma unroll
            for (int m = 0; m < 4; m++) {
                float p0 = exp2f(s[4 * m + 0]);
                float p1 = exp2f(s[4 * m + 1]);
                float p2 = exp2f(s[4 * m + 2]);
                float p3 = exp2f(s[4 * m + 3]);
                li += (p0 + p1) + (p2 + p3);
                uint2 pw;
                pw.x = pk2bf(p0, p1);
                pw.y = pk2bf(p2, p3);
                *(uint2*)(Pw + l5 * 72 + 32 * c + 8 * m + 4 * hi) = pw;
            }
        }
        // PV: A = P[q][ctx] (natural b128 from wave-private LDS), B = V^T
        bf16x8 pf[4];
#pragma unroll
        for (int kc = 0; kc < 4; kc++)
            pf[kc] = *(const bf16x8*)(Pw + l5 * 72 + kc * 16 + hi * 8);
#pragma unroll
        for (int dn = 0; dn < 2; dn++)
#pragma unroll
            for (int kc = 0; kc < 4; kc++)
                o[dn] = __builtin_amdgcn_mfma_f32_32x32x16_bf16(pf[kc], vf[dn][kc], o[dn], 0, 0, 0);
    }
}

__global__ __launch_bounds__(256) void attn_kernel(const ushort* __restrict__ q,
                                                   const ushort* __restrict__ Ka,
                                                   const ushort* __restrict__ VTa,
                                                   const ushort* __restrict__ Ks,
                                                   const ushort* __restrict__ VTs,
                                                   ushort* __restrict__ y) {
    __shared__ ushort Pl[4 * 32 * 72];
    int t = threadIdx.x;
    int wv = t >> 6, ln = t & 63, l5 = ln & 31, hi = ln >> 5;
    int h = blockIdx.y, bi = blockIdx.z;
    int q0 = blockIdx.x * 128 + wv * 32;
    bf16x8 aq[4];
    const ushort* qp = q + (size_t)(bi * NQ + q0 + l5) * DIM + h * 64 + hi * 8;
#pragma unroll
    for (int kd = 0; kd < 4; kd++) aq[kd] = *(const bf16x8*)(qp + kd * 16);
    ushort* Pw = Pl + wv * 32 * 72;

    f32x16 o[2];
#pragma unroll
    for (int dn = 0; dn < 2; dn++)
#pragma unroll
        for (int i = 0; i < 16; i++) o[dn][i] = 0.f;
    float li = 0.f;

    // lane-fixed base pointers (K: ctx rows; V^T: d rows)
    const ushort* kps = Ks + (size_t)(bi * MS + l5) * DIM + h * 64 + hi * 8;
    const ushort* vps = VTs + (size_t)bi * DIM * MS + (size_t)(h * 64 + l5) * MS + hi * 8;
    attn_ctx32(kps, vps, MS, aq, Pw, o, li, l5, hi);
    li += __shfl_xor(li, 32);
    float inv[16];
#pragma unroll
    for (int rg = 0; rg < 16; rg++)
        inv[rg] = 1.f / __shfl(li, (rg & 3) + 8 * (rg >> 2) + 4 * hi);
    float yv[2][16];
#pragma unroll
    for (int dn = 0; dn < 2; dn++)
#pragma unroll
        for (int rg = 0; rg < 16; rg++) yv[dn][rg] = o[dn][rg] * inv[rg];

#pragma unroll
    for (int dn = 0; dn < 2; dn++)
#pragma unroll
        for (int i = 0; i < 16; i++) o[dn][i] = 0.f;
    li = 0.f;
    const ushort* kpa = Ka + (size_t)(bi * MA + l5) * DIM + h * 64 + hi * 8;
    const ushort* vpa = VTa + (size_t)bi * DIM * MA + (size_t)(h * 64 + l5) * MA + hi * 8;
    attn_ctx32(kpa, vpa, MA, aq, Pw, o, li, l5, hi);
    li += __shfl_xor(li, 32);
#pragma unroll
    for (int rg = 0; rg < 16; rg++)
        inv[rg] = 1.f / __shfl(li, (rg & 3) + 8 * (rg >> 2) + 4 * hi);

    // O: lane holds d = 32*dn + l5, q = (rg&3)+8*(rg>>2)+4*hi
#pragma unroll
    for (int dn = 0; dn < 2; dn++)
#pragma unroll
        for (int rg = 0; rg < 16; rg++) {
            int qr = (rg & 3) + 8 * (rg >> 2) + 4 * hi;
            float ov = yv[dn][rg] + o[dn][rg] * inv[rg];
            y[(size_t)(bi * NQ + q0 + qr) * DIM + h * 64 + 32 * dn + l5] = f2b(ov);
        }
}

extern "C" void kernel_launch(void* const* d_in, const int* in_sizes, int n_in,
                              void* d_out, int out_size, void* d_ws, size_t ws_size,
                              hipStream_t stream) {
    const float* x   = (const float*)d_in[0];
    const float* ac  = (const float*)d_in[1];
    const float* scx = (const float*)d_in[2];
    const float* Wq  = (const float*)d_in[3];
    const float* bq  = (const float*)d_in[4];
    const float* Wka = (const float*)d_in[5];
    const float* bka = (const float*)d_in[6];
    const float* Wva = (const float*)d_in[7];
    const float* bva = (const float*)d_in[8];
    const float* Wks = (const float*)d_in[9];
    const float* bks = (const float*)d_in[10];
    const float* Wvs = (const float*)d_in[11];
    const float* bvs = (const float*)d_in[12];
    const float* Wp  = (const float*)d_in[13];
    const float* bp  = (const float*)d_in[14];

    ushort* wb   = (ushort*)d_ws;         // contiguous cast dst:
    ushort* wqb  = wb;                    // [6 weights][xb][acb][scxb]
    ushort* wkab = wb + 262144;
    ushort* wvab = wb + 2 * 262144;
    ushort* wksb = wb + 3 * 262144;
    ushort* wvsb = wb + 4 * 262144;
    ushort* wpb  = wb + 5 * 262144;
    ushort* xb   = wb + 6 * 262144;       // [8192][512]
    ushort* acb  = xb + 4194304;          // [8192][512]
    ushort* scxb = acb + 4194304;         // [1024][512]
    ushort* qb   = scxb + 524288;         // [8192][512] prescaled q
    ushort* kab  = qb + 4194304;          // [8192][512]
    ushort* vta  = kab + 4194304;         // [4][512][2048] V^T
    ushort* ksb  = vta + 4194304;         // [1024][512]
    ushort* vts  = ksb + 524288;          // [4][512][256]  V^T
    ushort* yb   = xb;                    // alias: x dead after gemm_fused

    cast_all<<<10240, 256, 0, stream>>>(Wq, Wka, Wva, Wks, Wvs, Wp, x, ac, scx, wb);

    GD gq   = {xb,   wqb,  bq,  qb,  0, 0,               512,  64, 4,  0,   0, 1, 0, 0};
    GD gka  = {acb,  wkab, bka, kab, 0, 0,               512,  64, 4,  256, 0, 0, 0, 0};
    GD gvta = {wvab, acb,  bva, vta, 2048L * 512, 512L * 2048, 2048, 4, 16, 512, 1, 0, 0, 0};
    GD gks  = {scxb, wksb, bks, ksb, 0, 0,               512,  8,  4,  768, 0, 0, 0, 0};
    GD gvts = {wvsb, scxb, bvs, vts, 256L * 512, 512L * 256,   256,  4,  2,  800, 1, 0, 0, 0};
    gemm_fused<<<832, 256, 0, stream>>>(gq, gka, gvta, gks, gvts);

    attn_kernel<<<dim3(16, 8, 4), 256, 0, stream>>>(qb, kab, vta, ksb, vts, yb);

    GD gpr = {yb, wpb, bp, d_out, 0, 0, 512, 64, 4, 0, 0, 0, 1, 0};
    GD gnv = {nullptr, nullptr, nullptr, nullptr, 0, 0, 0, 1, 1, 1 << 30, 0, 0, 0, 0};
    gemm_fused<<<256, 256, 0, stream>>>(gpr, gnv, gnv, gnv, gnv);
}

// Round 7
// 226.987 us; speedup vs baseline: 1.3540x; 1.3540x over previous
//
#include <hip/hip_runtime.h>

// R7: attention = staged-LDS (R5 base, R6's direct-global reverted) with
// (a) P entirely in registers: custom ctx<->k permutation of the PV MFMA makes
//     each lane's S^T quads land in its own A-frag slots (V staged with the
//     matching 8B-group swap so V reads stay b128),
// (b) single barrier/tile via K/V double-buffer + 2-tile register preload.
// GEMMs: R4 BK=32 fused version (R6 BK=64 was neutral/worse).
#define DIM 512
#define NQ 2048
#define MA 2048
#define MS 256
#define QSCALE 0.06375864651f  // 512^-0.5 * log2(e)

typedef __attribute__((ext_vector_type(8))) short bf16x8;
typedef __attribute__((ext_vector_type(4))) float f32x4;
typedef __attribute__((ext_vector_type(16))) float f32x16;

__device__ __forceinline__ ushort f2b(float f) {
    uint u = __float_as_uint(f);
    u = (u + 0x7fffu + ((u >> 16) & 1u)) >> 16;
    return (ushort)u;
}

__device__ __forceinline__ uint pk2bf(float a, float b) {
#if __has_builtin(__builtin_amdgcn_cvt_pk_bf16_f32)
    typedef __attribute__((ext_vector_type(2))) __bf16 bf2;
    bf2 r = __builtin_amdgcn_cvt_pk_bf16_f32(a, b);
    uint u;
    __builtin_memcpy(&u, &r, 4);
    return u;
#else
    return ((__float_as_uint(a) + 0x8000u) >> 16) |
           ((__float_as_uint(b) + 0x8000u) & 0xffff0000u);
#endif
}

__device__ __forceinline__ float fexp2(float x) {
#if __has_builtin(__builtin_amdgcn_exp2f)
    return __builtin_amdgcn_exp2f(x);
#else
    return exp2f(x);
#endif
}

__device__ __forceinline__ void gload16(const ushort* g, ushort* l) {
    __builtin_amdgcn_global_load_lds(
        (const __attribute__((address_space(1))) void*)g,
        (__attribute__((address_space(3))) void*)l, 16, 0, 0);
}

// ---- fused cast: 6 weights + x + ac + scx -> contiguous bf16 region ----
__global__ __launch_bounds__(256) void cast_all(const float* __restrict__ w0,
                                                const float* __restrict__ w1,
                                                const float* __restrict__ w2,
                                                const float* __restrict__ w3,
                                                const float* __restrict__ w4,
                                                const float* __restrict__ w5,
                                                const float* __restrict__ x,
                                                const float* __restrict__ ac,
                                                const float* __restrict__ scx,
                                                ushort* __restrict__ dst) {
    int i = blockIdx.x * 256 + threadIdx.x;  // float4 index, 2621440 total
    const float* s;
    int o;
    if (i < 393216) {
        int w = i >> 16;
        s = w < 3 ? (w == 0 ? w0 : (w == 1 ? w1 : w2))
                  : (w == 3 ? w3 : (w == 4 ? w4 : w5));
        o = i & 65535;
    } else if (i < 1441792) { s = x;   o = i - 393216; }
    else if (i < 2490368)   { s = ac;  o = i - 1441792; }
    else                    { s = scx; o = i - 2490368; }
    float4 v = ((const float4*)s)[o];
    ushort4 u;
    u.x = f2b(v.x); u.y = f2b(v.y); u.z = f2b(v.z); u.w = f2b(v.w);
    ((ushort4*)dst)[i] = u;
}

// ---- fused GEMM (R4): C = A @ B^T + bias, 128x128 tile, BK=32 ----
struct GD {
    const ushort* A; const ushort* B; const float* bias; void* out;
    long sB, sO;
    int N, bx, by, blk0, biasrow, scaleq, outf32, pad;
};

__global__ __launch_bounds__(256) void gemm_fused(GD d0, GD d1, GD d2, GD d3, GD d4) {
    __shared__ ushort At[128 * 32];
    __shared__ ushort Bt[128 * 32];
    GD d = d0;
    int bid = blockIdx.x;
    if (bid >= d1.blk0) d = d1;
    if (bid >= d2.blk0) d = d2;
    if (bid >= d3.blk0) d = d3;
    if (bid >= d4.blk0) d = d4;
    int local = bid - d.blk0;
    int x = local % d.bx;
    int rem = local / d.bx;
    int y = rem % d.by;
    int z = rem / d.by;

    int t = threadIdx.x;
    int wv = t >> 6, ln = t & 63, l = ln & 15, g = ln >> 4;
    int wrow = wv & 1, wcol = wv >> 1;
    int row0 = x * 128, col0 = y * 128;
    int srow = t >> 2;
    int slot = (t & 3) * 8;
    int sko = ((t ^ srow) & 3) * 8;        // XOR-swizzled global k-chunk
    int kc8 = ((g ^ (l & 3)) & 3) * 8;     // reader un-swizzle
    const ushort* Ab = d.A;
    const ushort* Bb = d.B + (size_t)z * d.sB;
    int N = d.N;

    f32x4 acc[4][4];
#pragma unroll
    for (int i = 0; i < 4; i++)
#pragma unroll
        for (int j = 0; j < 4; j++) acc[i][j] = (f32x4){0, 0, 0, 0};

    for (int k0 = 0; k0 < 512; k0 += 32) {
        __syncthreads();
#pragma unroll
        for (int c = 0; c < 2; c++) {
            gload16(Ab + (size_t)(row0 + srow + 64 * c) * 512 + k0 + sko,
                    At + (srow + 64 * c) * 32 + slot);
            gload16(Bb + (size_t)(col0 + srow + 64 * c) * 512 + k0 + sko,
                    Bt + (srow + 64 * c) * 32 + slot);
        }
        __syncthreads();
        bf16x8 ar[4], br[4];
#pragma unroll
        for (int i = 0; i < 4; i++)
            ar[i] = *(const bf16x8*)(At + (wrow * 64 + i * 16 + l) * 32 + kc8);
#pragma unroll
        for (int j = 0; j < 4; j++)
            br[j] = *(const bf16x8*)(Bt + (wcol * 64 + j * 16 + l) * 32 + kc8);
#pragma unroll
        for (int i = 0; i < 4; i++)
#pragma unroll
            for (int j = 0; j < 4; j++)
                acc[i][j] = __builtin_amdgcn_mfma_f32_16x16x32_bf16(ar[i], br[j], acc[i][j], 0, 0, 0);
    }
#pragma unroll
    for (int i = 0; i < 4; i++) {
#pragma unroll
        for (int j = 0; j < 4; j++) {
            int row = row0 + wrow * 64 + i * 16 + g * 4;
            int col = col0 + wcol * 64 + j * 16 + l;
#pragma unroll
            for (int r = 0; r < 4; r++) {
                float bv = d.biasrow ? d.bias[row + r] : d.bias[col];
                float o = acc[i][j][r] + bv;
                if (d.scaleq) o *= QSCALE;
                if (d.outf32)
                    ((float*)d.out + (size_t)z * d.sO)[(size_t)(row + r) * N + col] = o;
                else
                    ((ushort*)d.out + (size_t)z * d.sO)[(size_t)(row + r) * N + col] = f2b(o);
            }
        }
    }
}

// ---- attention: 32x32x16, K/V dbuf LDS (1 barrier/tile), P in registers ----
// PV k-permutation: k-slot (hi, j, kc) <-> ctx = 16kc + 4hi + (j&3) + 8(j>>2).
// Lane's S^T quads (ctx = 8m + 4hi + t + 32c) == its own A-frag slots.
// V staged with matching 8B-group swap so V-frag reads stay ds_read_b128.
__device__ __forceinline__ void attn_ctx32(const ushort* __restrict__ kg,
                                           const ushort* __restrict__ vg,
                                           int M, const bf16x8 (&aq)[4],
                                           ushort* __restrict__ Kl,
                                           ushort* __restrict__ Vl,
                                           f32x16 (&o)[2], float& li,
                                           int l5, int hi, int sr, int sc, int vbase) {
    int nt = M >> 6;
    bf16x8 k0 = *(const bf16x8*)kg;
    bf16x8 k1 = *(const bf16x8*)(kg + (size_t)32 * DIM);
    bf16x8 v0 = *(const bf16x8*)vg;
    bf16x8 v1 = *(const bf16x8*)(vg + (size_t)32 * M);
    __syncthreads();
    {   // tile 0 -> buf 0
        *(bf16x8*)(Kl + sr * 72 + sc) = k0;
        *(bf16x8*)(Kl + (sr + 32) * 72 + sc) = k1;
        union { bf16x8 v; uint2 h[2]; } cv;
        cv.v = v0;
        *(uint2*)(Vl + sr * 72 + vbase) = cv.h[0];
        *(uint2*)(Vl + sr * 72 + vbase + 8) = cv.h[1];
        cv.v = v1;
        *(uint2*)(Vl + (sr + 32) * 72 + vbase) = cv.h[0];
        *(uint2*)(Vl + (sr + 32) * 72 + vbase + 8) = cv.h[1];
    }
    if (nt > 1) {
        k0 = *(const bf16x8*)(kg + (size_t)64 * DIM);
        k1 = *(const bf16x8*)(kg + (size_t)96 * DIM);
        v0 = *(const bf16x8*)(vg + 64);
        v1 = *(const bf16x8*)(vg + (size_t)32 * M + 64);
    }
    for (int i = 0; i < nt; i++) {
        __syncthreads();
        if (i + 1 < nt) {
            ushort* Kb = Kl + ((i + 1) & 1) * (64 * 72);
            ushort* Vb = Vl + ((i + 1) & 1) * (64 * 72);
            *(bf16x8*)(Kb + sr * 72 + sc) = k0;
            *(bf16x8*)(Kb + (sr + 32) * 72 + sc) = k1;
            union { bf16x8 v; uint2 h[2]; } cv;
            cv.v = v0;
            *(uint2*)(Vb + sr * 72 + vbase) = cv.h[0];
            *(uint2*)(Vb + sr * 72 + vbase + 8) = cv.h[1];
            cv.v = v1;
            *(uint2*)(Vb + (sr + 32) * 72 + vbase) = cv.h[0];
            *(uint2*)(Vb + (sr + 32) * 72 + vbase + 8) = cv.h[1];
        }
        if (i + 2 < nt) {
            size_t off = (size_t)(i + 2) * 64;
            k0 = *(const bf16x8*)(kg + off * DIM);
            k1 = *(const bf16x8*)(kg + (off + 32) * DIM);
            v0 = *(const bf16x8*)(vg + off);
            v1 = *(const bf16x8*)(vg + (size_t)32 * M + off);
        }
        const ushort* Kc = Kl + (i & 1) * (64 * 72);
        const ushort* Vc = Vl + (i & 1) * (64 * 72);
        uint2 pq[2][4];
#pragma unroll
        for (int c = 0; c < 2; c++) {
            bf16x8 kf[4];
#pragma unroll
            for (int kd = 0; kd < 4; kd++)
                kf[kd] = *(const bf16x8*)(Kc + (32 * c + l5) * 72 + kd * 16 + hi * 8);
            f32x16 s;
#pragma unroll
            for (int ii = 0; ii < 16; ii++) s[ii] = 0.f;
#pragma unroll
            for (int kd = 0; kd < 4; kd++)
                s = __builtin_amdgcn_mfma_f32_32x32x16_bf16(kf[kd], aq[kd], s, 0, 0, 0);
#pragma unroll
            for (int m = 0; m < 4; m++) {
                float p0 = fexp2(s[4 * m + 0]);
                float p1 = fexp2(s[4 * m + 1]);
                float p2 = fexp2(s[4 * m + 2]);
                float p3 = fexp2(s[4 * m + 3]);
                li += (p0 + p1) + (p2 + p3);
                pq[c][m].x = pk2bf(p0, p1);
                pq[c][m].y = pk2bf(p2, p3);
            }
        }
#pragma unroll
        for (int kc = 0; kc < 4; kc++) {
            int c = kc >> 1, m0 = 2 * (kc & 1);
            union { bf16x8 v; uint u[4]; } w;
            w.u[0] = pq[c][m0].x;     w.u[1] = pq[c][m0].y;
            w.u[2] = pq[c][m0 + 1].x; w.u[3] = pq[c][m0 + 1].y;
#pragma unroll
            for (int dn = 0; dn < 2; dn++) {
                bf16x8 vf = *(const bf16x8*)(Vc + (32 * dn + l5) * 72 + kc * 16 + hi * 8);
                o[dn] = __builtin_amdgcn_mfma_f32_32x32x16_bf16(w.v, vf, o[dn], 0, 0, 0);
            }
        }
    }
}

__global__ __launch_bounds__(256) void attn_kernel(const ushort* __restrict__ q,
                                                   const ushort* __restrict__ Ka,
                                                   const ushort* __restrict__ VTa,
                                                   const ushort* __restrict__ Ks,
                                                   const ushort* __restrict__ VTs,
                                                   ushort* __restrict__ y) {
    __shared__ ushort Kl[2 * 64 * 72];
    __shared__ ushort Vl[2 * 64 * 72];
    int t = threadIdx.x;
    int wv = t >> 6, ln = t & 63, l5 = ln & 31, hi = ln >> 5;
    int h = blockIdx.y, bi = blockIdx.z;
    int q0 = blockIdx.x * 128 + wv * 32;
    bf16x8 aq[4];
    const ushort* qp = q + (size_t)(bi * NQ + q0 + l5) * DIM + h * 64 + hi * 8;
#pragma unroll
    for (int kd = 0; kd < 4; kd++) aq[kd] = *(const bf16x8*)(qp + kd * 16);
    int sr = t >> 3, sc = (t & 7) * 8;
    int vbase = (sc >> 4) * 16 + ((sc >> 3) & 1) * 4;  // permuted V slot base

    f32x16 o[2];
#pragma unroll
    for (int dn = 0; dn < 2; dn++)
#pragma unroll
        for (int i = 0; i < 16; i++) o[dn][i] = 0.f;
    float li = 0.f;

    // singer (short) first
    attn_ctx32(Ks + (size_t)bi * MS * DIM + (size_t)sr * DIM + h * 64 + sc,
               VTs + (size_t)bi * DIM * MS + (size_t)(h * 64 + sr) * MS + sc,
               MS, aq, Kl, Vl, o, li, l5, hi, sr, sc, vbase);
    li += __shfl_xor(li, 32);
    float inv[16];
#pragma unroll
    for (int rg = 0; rg < 16; rg++)
        inv[rg] = 1.f / __shfl(li, (rg & 3) + 8 * (rg >> 2) + 4 * hi);
    float yv[2][16];
#pragma unroll
    for (int dn = 0; dn < 2; dn++)
#pragma unroll
        for (int rg = 0; rg < 16; rg++) yv[dn][rg] = o[dn][rg] * inv[rg];

#pragma unroll
    for (int dn = 0; dn < 2; dn++)
#pragma unroll
        for (int i = 0; i < 16; i++) o[dn][i] = 0.f;
    li = 0.f;
    attn_ctx32(Ka + (size_t)bi * MA * DIM + (size_t)sr * DIM + h * 64 + sc,
               VTa + (size_t)bi * DIM * MA + (size_t)(h * 64 + sr) * MA + sc,
               MA, aq, Kl, Vl, o, li, l5, hi, sr, sc, vbase);
    li += __shfl_xor(li, 32);
#pragma unroll
    for (int rg = 0; rg < 16; rg++)
        inv[rg] = 1.f / __shfl(li, (rg & 3) + 8 * (rg >> 2) + 4 * hi);

    // O: lane holds d = 32*dn + l5, q = (rg&3)+8*(rg>>2)+4*hi
#pragma unroll
    for (int dn = 0; dn < 2; dn++)
#pragma unroll
        for (int rg = 0; rg < 16; rg++) {
            int qr = (rg & 3) + 8 * (rg >> 2) + 4 * hi;
            float ov = yv[dn][rg] + o[dn][rg] * inv[rg];
            y[(size_t)(bi * NQ + q0 + qr) * DIM + h * 64 + 32 * dn + l5] = f2b(ov);
        }
}

extern "C" void kernel_launch(void* const* d_in, const int* in_sizes, int n_in,
                              void* d_out, int out_size, void* d_ws, size_t ws_size,
                              hipStream_t stream) {
    const float* x   = (const float*)d_in[0];
    const float* ac  = (const float*)d_in[1];
    const float* scx = (const float*)d_in[2];
    const float* Wq  = (const float*)d_in[3];
    const float* bq  = (const float*)d_in[4];
    const float* Wka = (const float*)d_in[5];
    const float* bka = (const float*)d_in[6];
    const float* Wva = (const float*)d_in[7];
    const float* bva = (const float*)d_in[8];
    const float* Wks = (const float*)d_in[9];
    const float* bks = (const float*)d_in[10];
    const float* Wvs = (const float*)d_in[11];
    const float* bvs = (const float*)d_in[12];
    const float* Wp  = (const float*)d_in[13];
    const float* bp  = (const float*)d_in[14];

    ushort* wb   = (ushort*)d_ws;         // contiguous cast dst:
    ushort* wqb  = wb;                    // [6 weights][xb][acb][scxb]
    ushort* wkab = wb + 262144;
    ushort* wvab = wb + 2 * 262144;
    ushort* wksb = wb + 3 * 262144;
    ushort* wvsb = wb + 4 * 262144;
    ushort* wpb  = wb + 5 * 262144;
    ushort* xb   = wb + 6 * 262144;       // [8192][512]
    ushort* acb  = xb + 4194304;          // [8192][512]
    ushort* scxb = acb + 4194304;         // [1024][512]
    ushort* qb   = scxb + 524288;         // [8192][512] prescaled q
    ushort* kab  = qb + 4194304;          // [8192][512]
    ushort* vta  = kab + 4194304;         // [4][512][2048] V^T
    ushort* ksb  = vta + 4194304;         // [1024][512]
    ushort* vts  = ksb + 524288;          // [4][512][256]  V^T
    ushort* yb   = xb;                    // alias: x dead after gemm_fused

    cast_all<<<10240, 256, 0, stream>>>(Wq, Wka, Wva, Wks, Wvs, Wp, x, ac, scx, wb);

    GD gq   = {xb,   wqb,  bq,  qb,  0, 0,               512,  64, 4,  0,   0, 1, 0, 0};
    GD gka  = {acb,  wkab, bka, kab, 0, 0,               512,  64, 4,  256, 0, 0, 0, 0};
    GD gvta = {wvab, acb,  bva, vta, 2048L * 512, 512L * 2048, 2048, 4, 16, 512, 1, 0, 0, 0};
    GD gks  = {scxb, wksb, bks, ksb, 0, 0,               512,  8,  4,  768, 0, 0, 0, 0};
    GD gvts = {wvsb, scxb, bvs, vts, 256L * 512, 512L * 256,   256,  4,  2,  800, 1, 0, 0, 0};
    gemm_fused<<<832, 256, 0, stream>>>(gq, gka, gvta, gks, gvts);

    attn_kernel<<<dim3(16, 8, 4), 256, 0, stream>>>(qb, kab, vta, ksb, vts, yb);

    GD gpr = {yb, wpb, bp, d_out, 0, 0, 512, 64, 4, 0, 0, 0, 1, 0};
    GD gnv = {nullptr, nullptr, nullptr, nullptr, 0, 0, 0, 1, 1, 1 << 30, 0, 0, 0, 0};
    gemm_fused<<<256, 256, 0, stream>>>(gpr, gnv, gnv, gnv, gnv);
}